// Round 3
// baseline (4582.044 us; speedup 1.0000x reference)
//
#include <hip/hip_runtime.h>
#include <hip/hip_bf16.h>

// Problem constants (fixed by the reference)
#define BB 1024   // batch
#define NN 512    // variable dim
#define MI 512    // inequality count
#define ME 16     // equality count
#define ALPHA 0.05f
#define NS_ITERS 10
#define ADMM_IT 15

// ---------------- dtype auto-detect ----------------
// Inputs are either bf16 or f32 (reference is f32; dataset may have bf16-ified).
// Inspect G's raw half-words under bf16 interpretation: true-bf16 G entries are
// ~N(0,1/512) -> |G| < 0.3, exponent field < 0x7D, ZERO insane values.
// f32 misread as bf16: even elements are float low-halves -> exponent field is
// uniform middle-mantissa bits -> ~49% have |v|>=16 or NaN. Threshold 64.
__global__ void detect_dtype_k(const unsigned short* __restrict__ g_raw,
                               float* __restrict__ flag) {
    __shared__ int cnt;
    int tid = threadIdx.x;
    if (tid == 0) cnt = 0;
    __syncthreads();
    int local = 0;
    for (int i = tid; i < 8192; i += 256) {
        int e = (g_raw[i] >> 7) & 0xFF;   // bf16 exponent field
        if (e >= 0x83) local++;           // |v| >= 16, inf, or NaN
    }
    atomicAdd(&cnt, local);
    __syncthreads();
    if (tid == 0) flag[0] = (cnt < 64) ? 1.0f : 0.0f;  // 1 => bf16 inputs
}

// ---------------- elementwise / small kernels ----------------

__global__ void ingest_k(const void* __restrict__ src, float* __restrict__ dst,
                         int n, const float* __restrict__ flag) {
    int i = blockIdx.x * 256 + threadIdx.x;
    if (i >= n) return;
    if (flag[0] > 0.5f) dst[i] = __bfloat162float(((const __hip_bfloat16*)src)[i]);
    else                dst[i] = ((const float*)src)[i];
}

__global__ void emit_k(const float* __restrict__ src, void* __restrict__ dst,
                       int n, const float* __restrict__ flag) {
    int i = blockIdx.x * 256 + threadIdx.x;
    if (i >= n) return;
    if (flag[0] > 0.5f) ((__hip_bfloat16*)dst)[i] = __float2bfloat16(src[i]);
    else                ((float*)dst)[i] = src[i];
}

__global__ void pgd_step_k(const float* __restrict__ z, const float* __restrict__ c,
                           float* __restrict__ x, int n) {
    int i = blockIdx.x * 256 + threadIdx.x;
    if (i < n) x[i] = (1.0f - ALPHA) * z[i] + ALPHA * c[i];
}

// transpose 512x512
__global__ void transpose512(const float* __restrict__ src, float* __restrict__ dst) {
    __shared__ float t[32][33];
    int bx = blockIdx.x * 32, by = blockIdx.y * 32;
    int tx = threadIdx.x & 31, ty0 = threadIdx.x >> 5;  // 256 threads
    for (int i = ty0; i < 32; i += 8) t[i][tx] = src[(by + i) * NN + bx + tx];
    __syncthreads();
    for (int i = ty0; i < 32; i += 8) dst[(bx + i) * NN + by + tx] = t[tx][i];
}

// row |.| sums of M (512x512) -> rs[512]
__global__ void row_abs_sum_k(const float* __restrict__ Mm, float* __restrict__ rs) {
    int row = blockIdx.x;
    int lane = threadIdx.x;  // 64
    float s = 0.f;
    for (int j = lane; j < NN; j += 64) s += fabsf(Mm[row * NN + j]);
    for (int off = 32; off; off >>= 1) s += __shfl_down(s, off);
    if (lane == 0) rs[row] = s;
}

// c0 = 2/(1 + max(rs))
__global__ void max_c0_k(const float* __restrict__ rs, float* __restrict__ c0s) {
    int lane = threadIdx.x;  // 64
    float m = 0.f;
    for (int i = lane; i < NN; i += 64) m = fmaxf(m, rs[i]);
    for (int off = 32; off; off >>= 1) m = fmaxf(m, __shfl_down(m, off));
    if (lane == 0) c0s[0] = 2.0f / (1.0f + m);
}

__global__ void init_X_k(float* __restrict__ X, const float* __restrict__ c0s) {
    int idx = blockIdx.x * 256 + threadIdx.x;
    if (idx < NN * NN) {
        int i = idx / NN, j = idx - i * NN;
        X[idx] = (i == j) ? c0s[0] : 0.f;
    }
}

// 16x16 inverse via Gauss-Jordan, one wave, row r per lane.
__global__ void inv16_k(const float* __restrict__ S, float* __restrict__ Si) {
    int r = threadIdx.x;  // 64 lanes, rows 0..15 live
    float a[16], bI[16];
    #pragma unroll
    for (int j = 0; j < 16; ++j) {
        a[j]  = (r < 16) ? S[r * 16 + j] : 0.f;
        bI[j] = (r < 16 && j == r) ? 1.f : 0.f;
    }
    for (int k = 0; k < 16; ++k) {
        float pa[16], pb[16];
        #pragma unroll
        for (int j = 0; j < 16; ++j) { pa[j] = __shfl(a[j], k); pb[j] = __shfl(bI[j], k); }
        float inv = 1.0f / pa[k];
        if (r == k) {
            #pragma unroll
            for (int j = 0; j < 16; ++j) { a[j] = pa[j] * inv; bI[j] = pb[j] * inv; }
        } else {
            float f = a[k] * inv;
            #pragma unroll
            for (int j = 0; j < 16; ++j) {
                a[j]  = fmaf(-f, pa[j], a[j]);
                bI[j] = fmaf(-f, pb[j], bI[j]);
            }
        }
    }
    if (r < 16)
        #pragma unroll
        for (int j = 0; j < 16; ++j) Si[r * 16 + j] = bI[j];
}

// ---------------- generic NT GEMM ----------------
// C[m,n] = sum_k A[m,k]*B[n,k], A:[M,K] ld=K, B:[N,K] ld=K, C:[M,N] ld=N
// mode 0: C = acc
// mode 1: C = acc + (m==n)                       (M = I + G^T G)
// mode 2: C = 2*E[m,n] - acc                     (Newton-Schulz update)
// mode 3: C = E[m,n] - acc                       (W1 = Minv - T1 Y^T)
// mode 4: C = acc + v1[n]                        (q0 = x@R^T + g0)
// mode 6: C = max(0, v1[n] - acc), C2 = 0        (s-init, u-init)
#define TBM 64
#define TBN 64
#define TBK 16

__global__ __launch_bounds__(256) void gemm_nt(
    const float* __restrict__ A, const float* __restrict__ B, float* __restrict__ C,
    int M, int N, int K, int mode,
    const float* __restrict__ E, const float* __restrict__ v1, float* __restrict__ C2)
{
    __shared__ float As[TBK][TBM + 4];
    __shared__ float Bs[TBK][TBN + 4];
    const int tid = threadIdx.x;
    const int lk = tid & 15;
    const int lm = tid >> 4;
    const int m0 = blockIdx.y * TBM;
    const int n0 = blockIdx.x * TBN;
    const int tx = tid & 15, ty = tid >> 4;

    float acc[4][4] = {{0.f, 0.f, 0.f, 0.f}, {0.f, 0.f, 0.f, 0.f},
                       {0.f, 0.f, 0.f, 0.f}, {0.f, 0.f, 0.f, 0.f}};

    for (int k0 = 0; k0 < K; k0 += TBK) {
        int kk = k0 + lk;
        #pragma unroll
        for (int i = 0; i < 4; ++i) {
            int m = m0 + lm + i * 16;
            As[lk][lm + i * 16] = (m < M && kk < K) ? A[(size_t)m * K + kk] : 0.f;
            int n = n0 + lm + i * 16;
            Bs[lk][lm + i * 16] = (n < N && kk < K) ? B[(size_t)n * K + kk] : 0.f;
        }
        __syncthreads();
        #pragma unroll
        for (int k = 0; k < TBK; ++k) {
            float av[4], bv[4];
            #pragma unroll
            for (int i = 0; i < 4; ++i) av[i] = As[k][ty * 4 + i];
            #pragma unroll
            for (int j = 0; j < 4; ++j) bv[j] = Bs[k][tx * 4 + j];
            #pragma unroll
            for (int i = 0; i < 4; ++i)
                #pragma unroll
                for (int j = 0; j < 4; ++j)
                    acc[i][j] = fmaf(av[i], bv[j], acc[i][j]);
        }
        __syncthreads();
    }

    #pragma unroll
    for (int i = 0; i < 4; ++i) {
        #pragma unroll
        for (int j = 0; j < 4; ++j) {
            int m = m0 + ty * 4 + i;
            int n = n0 + tx * 4 + j;
            if (m >= M || n >= N) continue;
            size_t idx = (size_t)m * N + n;
            float a = acc[i][j];
            if (mode == 0) {
                C[idx] = a;
            } else if (mode == 1) {
                C[idx] = a + ((m == n) ? 1.0f : 0.0f);
            } else if (mode == 2) {
                C[idx] = 2.0f * E[idx] - a;
            } else if (mode == 3) {
                C[idx] = E[idx] - a;
            } else if (mode == 4) {
                C[idx] = a + v1[n];
            } else {  // mode 6
                C[idx] = fmaxf(0.f, v1[n] - a);
                C2[idx] = 0.f;
            }
        }
    }
}

// ---------------- fused ADMM step GEMM ----------------
// Fixed shape: [BB, MI or NN] x K=MI. A-operand built on the fly: t[m,k] = h[k]-s[m,k]-u[m,k]
// mode 0 (iteration): Gz = acc + add1; s' = max(0, h[n]-Gz-u); u' = u + Gz + s' - h[n]
// mode 1 (final z):   z = acc + add1[m,n] + vn[n]
__global__ __launch_bounds__(256) void admm_step(
    const float* __restrict__ s_in, const float* __restrict__ u_in,
    const float* __restrict__ Bm, const float* __restrict__ add1,
    const float* __restrict__ hv, const float* __restrict__ vn,
    float* __restrict__ o1, float* __restrict__ o2, int mode)
{
    __shared__ float As[TBK][TBM + 4];
    __shared__ float Bs[TBK][TBN + 4];
    const int tid = threadIdx.x;
    const int lk = tid & 15;
    const int lm = tid >> 4;
    const int m0 = blockIdx.y * TBM;
    const int n0 = blockIdx.x * TBN;
    const int tx = tid & 15, ty = tid >> 4;

    float acc[4][4] = {{0.f, 0.f, 0.f, 0.f}, {0.f, 0.f, 0.f, 0.f},
                       {0.f, 0.f, 0.f, 0.f}, {0.f, 0.f, 0.f, 0.f}};

    for (int k0 = 0; k0 < MI; k0 += TBK) {
        int kk = k0 + lk;
        float hk = hv[kk];
        #pragma unroll
        for (int i = 0; i < 4; ++i) {
            size_t ai = (size_t)(m0 + lm + i * 16) * MI + kk;
            As[lk][lm + i * 16] = hk - s_in[ai] - u_in[ai];
            Bs[lk][lm + i * 16] = Bm[(size_t)(n0 + lm + i * 16) * MI + kk];
        }
        __syncthreads();
        #pragma unroll
        for (int k = 0; k < TBK; ++k) {
            float av[4], bv[4];
            #pragma unroll
            for (int i = 0; i < 4; ++i) av[i] = As[k][ty * 4 + i];
            #pragma unroll
            for (int j = 0; j < 4; ++j) bv[j] = Bs[k][tx * 4 + j];
            #pragma unroll
            for (int i = 0; i < 4; ++i)
                #pragma unroll
                for (int j = 0; j < 4; ++j)
                    acc[i][j] = fmaf(av[i], bv[j], acc[i][j]);
        }
        __syncthreads();
    }

    #pragma unroll
    for (int i = 0; i < 4; ++i) {
        #pragma unroll
        for (int j = 0; j < 4; ++j) {
            int m = m0 + ty * 4 + i;
            int n = n0 + tx * 4 + j;
            size_t idx = (size_t)m * NN + n;  // NN == MI == 512
            float a = acc[i][j] + add1[idx];
            if (mode == 0) {
                float uv = u_in[idx];
                float hn = hv[n];
                float s2 = fmaxf(0.f, hn - a - uv);
                o1[idx] = s2;
                o2[idx] = uv + a + s2 - hn;
            } else {
                o1[idx] = a + vn[n];
            }
        }
    }
}

// ---------------- host launcher ----------------

extern "C" void kernel_launch(void* const* d_in, const int* in_sizes, int n_in,
                              void* d_out, int out_size, void* d_ws, size_t ws_size,
                              hipStream_t stream) {
    const void* c_raw = d_in[0];
    const void* G_raw = d_in[1];
    const void* h_raw = d_in[2];
    const void* A_raw = d_in[3];
    const void* b_raw = d_in[4];

    float* w = (float*)d_ws;
    size_t o = 0;
    auto alloc = [&](size_t n) { float* p = w + o; o += (n + 63) & ~(size_t)63; return p; };

    float* cF = alloc(BB * NN);
    float* GF = alloc(MI * NN);
    float* GT = alloc(NN * MI);   // later holds R
    float* AF = alloc(ME * NN);
    float* hF = alloc(MI);
    float* bF = alloc(ME);
    float* Mm = alloc(NN * NN);   // later holds Q
    float* X  = alloc(NN * NN);   // Minv after Newton-Schulz
    float* X2 = alloc(NN * NN);   // later holds RT
    float* Ub = alloc(NN * NN);   // NS temp, later holds W1
    float* Y  = alloc(NN * ME);
    float* YT = alloc(ME * NN);
    float* T1 = alloc(NN * ME);
    float* Sm = alloc(ME * ME);
    float* Si = alloc(ME * ME);
    float* zb = alloc(NN);
    float* g0 = alloc(MI);
    float* rs = alloc(NN);
    float* c0s = alloc(16);
    float* dtf = alloc(16);       // dtype flag: 1 => bf16 inputs, 0 => f32
    float* xb = alloc(BB * NN);
    float* q0 = alloc(BB * MI);
    float* xW = alloc(BB * NN);
    float* s0 = alloc(BB * MI);
    float* u0 = alloc(BB * MI);
    float* s1 = alloc(BB * MI);
    float* u1 = alloc(BB * MI);
    float* zf = alloc(BB * NN);

    dim3 blk(256);
    auto cdiv = [](int a, int b) { return (a + b - 1) / b; };

    // --- detect input dtype from G's raw bits ---
    detect_dtype_k<<<1, 256, 0, stream>>>((const unsigned short*)G_raw, dtf);

    // --- ingest (bf16 or f32) -> f32 ---
    ingest_k<<<cdiv(BB * NN, 256), blk, 0, stream>>>(c_raw, cF, BB * NN, dtf);
    ingest_k<<<cdiv(MI * NN, 256), blk, 0, stream>>>(G_raw, GF, MI * NN, dtf);
    ingest_k<<<cdiv(MI, 256),      blk, 0, stream>>>(h_raw, hF, MI, dtf);
    ingest_k<<<cdiv(ME * NN, 256), blk, 0, stream>>>(A_raw, AF, ME * NN, dtf);
    ingest_k<<<cdiv(ME, 256),      blk, 0, stream>>>(b_raw, bF, ME, dtf);

    // --- precompute: M = I + G^T G ---
    transpose512<<<dim3(16, 16), blk, 0, stream>>>(GF, GT);
    gemm_nt<<<dim3(8, 8), blk, 0, stream>>>(GT, GT, Mm, NN, NN, MI, 1, nullptr, nullptr, nullptr);

    // --- Newton-Schulz: X -> Minv ---
    row_abs_sum_k<<<NN, 64, 0, stream>>>(Mm, rs);
    max_c0_k<<<1, 64, 0, stream>>>(rs, c0s);
    init_X_k<<<cdiv(NN * NN, 256), blk, 0, stream>>>(X, c0s);
    float* Xa = X; float* Xb = X2;
    for (int it = 0; it < NS_ITERS; ++it) {
        gemm_nt<<<dim3(8, 8), blk, 0, stream>>>(Xa, Mm, Ub, NN, NN, NN, 0, nullptr, nullptr, nullptr);
        gemm_nt<<<dim3(8, 8), blk, 0, stream>>>(Ub, Xa, Xb, NN, NN, NN, 2, Xa, nullptr, nullptr);
        float* t = Xa; Xa = Xb; Xb = t;
    }
    // NS_ITERS even -> result in X (Xa == X)

    // --- Schur pieces: Y = Minv A^T, S = A Minv A^T, Sinv ---
    gemm_nt<<<dim3(1, 8), blk, 0, stream>>>(Xa, AF, Y,  NN, ME, NN, 0, nullptr, nullptr, nullptr);
    gemm_nt<<<dim3(8, 1), blk, 0, stream>>>(AF, Xa, YT, ME, NN, NN, 0, nullptr, nullptr, nullptr);
    gemm_nt<<<dim3(1, 1), blk, 0, stream>>>(AF, YT, Sm, ME, ME, NN, 0, nullptr, nullptr, nullptr);
    inv16_k<<<1, 64, 0, stream>>>(Sm, Si);
    gemm_nt<<<dim3(1, 8), blk, 0, stream>>>(Y, Si, T1, NN, ME, ME, 0, nullptr, nullptr, nullptr);
    // zb = T1 @ b
    gemm_nt<<<dim3(1, 8), blk, 0, stream>>>(T1, bF, zb, NN, 1, ME, 0, nullptr, nullptr, nullptr);
    // W1 = Minv - T1 Y^T  (into Ub)
    gemm_nt<<<dim3(8, 8), blk, 0, stream>>>(T1, Y, Ub, NN, NN, ME, 3, Xa, nullptr, nullptr);
    // R = G W1 (into GT buffer), RT (into X2 buffer), Q = R G^T (into Mm buffer)
    gemm_nt<<<dim3(8, 8), blk, 0, stream>>>(GF, Ub, GT, MI, NN, NN, 0, nullptr, nullptr, nullptr);
    transpose512<<<dim3(16, 16), blk, 0, stream>>>(GT, X2);
    gemm_nt<<<dim3(8, 8), blk, 0, stream>>>(GT, GF, Mm, MI, MI, NN, 0, nullptr, nullptr, nullptr);
    // g0 = G @ zb
    gemm_nt<<<dim3(1, 8), blk, 0, stream>>>(GF, zb, g0, MI, 1, NN, 0, nullptr, nullptr, nullptr);

    float* Rm = GT;   // R
    float* RT = X2;   // R^T
    float* Qm = Mm;   // Q
    float* W1 = Ub;   // W1

    dim3 gBig(8, 16);  // [1024 x 512] outputs

    // --- 4 projections: x0 = c, then PGD points ---
    for (int p = 0; p < 4; ++p) {
        const float* xp = (p == 0) ? cF : xb;
        // s0 = max(0, h - x G^T), u0 = 0
        gemm_nt<<<gBig, blk, 0, stream>>>(xp, GF, s0, BB, MI, NN, 6, nullptr, hF, u0);
        // q0 = x @ R^T + g0
        gemm_nt<<<gBig, blk, 0, stream>>>(xp, Rm, q0, BB, MI, NN, 4, nullptr, g0, nullptr);
        // xW = x @ W1
        gemm_nt<<<gBig, blk, 0, stream>>>(xp, W1, xW, BB, NN, NN, 0, nullptr, nullptr, nullptr);

        float* sa = s0; float* ua = u0; float* sb = s1; float* ub = u1;
        for (int it = 0; it < ADMM_IT; ++it) {
            admm_step<<<gBig, blk, 0, stream>>>(sa, ua, Qm, q0, hF, nullptr, sb, ub, 0);
            float* t;
            t = sa; sa = sb; sb = t;
            t = ua; ua = ub; ub = t;
        }
        // final z = t @ R + xW + zb
        admm_step<<<gBig, blk, 0, stream>>>(sa, ua, RT, xW, hF, zb, zf, nullptr, 1);

        if (p < 3) {
            pgd_step_k<<<cdiv(BB * NN, 256), blk, 0, stream>>>(zf, cF, xb, BB * NN);
        } else {
            emit_k<<<cdiv(BB * NN, 256), blk, 0, stream>>>(zf, d_out, BB * NN, dtf);
        }
    }
}

// Round 4
// 1840.066 us; speedup vs baseline: 2.4902x; 2.4902x over previous
//
#include <hip/hip_runtime.h>
#include <hip/hip_bf16.h>

// Problem constants (fixed by the reference)
#define BB 1024   // batch
#define NN 512    // variable dim
#define MI 512    // inequality count
#define ME 16     // equality count
#define ALPHA 0.05f
#define NS_ITERS 10
#define ADMM_IT 15

typedef __attribute__((ext_vector_type(8))) short short8;   // 8 bf16 = 4 VGPRs
typedef __attribute__((ext_vector_type(4))) float float4v;  // MFMA accumulator

__device__ inline short f2bf(float v) {
    __hip_bfloat16 b = __float2bfloat16(v);
    return *reinterpret_cast<short*>(&b);
}
__device__ inline float bf2f(short s) {
    __hip_bfloat16 b = *reinterpret_cast<__hip_bfloat16*>(&s);
    return __bfloat162float(b);
}
// split f32 -> hi/lo bf16 planes (hi + lo carries ~16 mantissa bits)
__device__ inline void split_store(float v, short* __restrict__ hi, short* __restrict__ lo, size_t idx) {
    short h = f2bf(v);
    hi[idx] = h;
    lo[idx] = f2bf(v - bf2f(h));
}

// ---------------- dtype auto-detect (bf16 vs f32 inputs) ----------------
__global__ void detect_dtype_k(const unsigned short* __restrict__ g_raw,
                               float* __restrict__ flag) {
    __shared__ int cnt;
    int tid = threadIdx.x;
    if (tid == 0) cnt = 0;
    __syncthreads();
    int local = 0;
    for (int i = tid; i < 8192; i += 256) {
        int e = (g_raw[i] >> 7) & 0xFF;
        if (e >= 0x83) local++;   // |v|>=16, inf, or NaN under bf16 view
    }
    atomicAdd(&cnt, local);
    __syncthreads();
    if (tid == 0) flag[0] = (cnt < 64) ? 1.0f : 0.0f;  // 1 => bf16 inputs
}

// ---------------- elementwise ----------------
__global__ void ingest_k(const void* __restrict__ src, float* __restrict__ dst,
                         int n, const float* __restrict__ flag) {
    int i = blockIdx.x * 256 + threadIdx.x;
    if (i >= n) return;
    if (flag[0] > 0.5f) dst[i] = __bfloat162float(((const __hip_bfloat16*)src)[i]);
    else                dst[i] = ((const float*)src)[i];
}

__global__ void emit_k(const float* __restrict__ src, void* __restrict__ dst,
                       int n, const float* __restrict__ flag) {
    int i = blockIdx.x * 256 + threadIdx.x;
    if (i >= n) return;
    if (flag[0] > 0.5f) ((__hip_bfloat16*)dst)[i] = __float2bfloat16(src[i]);
    else                ((float*)dst)[i] = src[i];
}

// f32 -> hi/lo bf16 planes
__global__ void split_k(const float* __restrict__ src, short* __restrict__ hi,
                        short* __restrict__ lo, int n) {
    int i = blockIdx.x * 256 + threadIdx.x;
    if (i < n) split_store(src[i], hi, lo, i);
}

// x = (1-a)z + a c, written directly as hi/lo planes (x only feeds GEMMs)
__global__ void pgd_split_k(const float* __restrict__ z, const float* __restrict__ c,
                            short* __restrict__ xhi, short* __restrict__ xlo, int n) {
    int i = blockIdx.x * 256 + threadIdx.x;
    if (i < n) split_store((1.0f - ALPHA) * z[i] + ALPHA * c[i], xhi, xlo, i);
}

// transpose 512x512
__global__ void transpose512(const float* __restrict__ src, float* __restrict__ dst) {
    __shared__ float t[32][33];
    int bx = blockIdx.x * 32, by = blockIdx.y * 32;
    int tx = threadIdx.x & 31, ty0 = threadIdx.x >> 5;
    for (int i = ty0; i < 32; i += 8) t[i][tx] = src[(by + i) * NN + bx + tx];
    __syncthreads();
    for (int i = ty0; i < 32; i += 8) dst[(bx + i) * NN + by + tx] = t[tx][i];
}

__global__ void row_abs_sum_k(const float* __restrict__ Mm, float* __restrict__ rs) {
    int row = blockIdx.x, lane = threadIdx.x;
    float s = 0.f;
    for (int j = lane; j < NN; j += 64) s += fabsf(Mm[row * NN + j]);
    for (int off = 32; off; off >>= 1) s += __shfl_down(s, off);
    if (lane == 0) rs[row] = s;
}

__global__ void max_c0_k(const float* __restrict__ rs, float* __restrict__ c0s) {
    int lane = threadIdx.x;
    float m = 0.f;
    for (int i = lane; i < NN; i += 64) m = fmaxf(m, rs[i]);
    for (int off = 32; off; off >>= 1) m = fmaxf(m, __shfl_down(m, off));
    if (lane == 0) c0s[0] = 2.0f / (1.0f + m);
}

__global__ void init_X_k(float* __restrict__ X, short* __restrict__ Xhi,
                         short* __restrict__ Xlo, const float* __restrict__ c0s) {
    int idx = blockIdx.x * 256 + threadIdx.x;
    if (idx < NN * NN) {
        int i = idx / NN, j = idx - i * NN;
        float v = (i == j) ? c0s[0] : 0.f;
        X[idx] = v;
        split_store(v, Xhi, Xlo, idx);
    }
}

// 16x16 inverse via Gauss-Jordan, one wave
__global__ void inv16_k(const float* __restrict__ S, float* __restrict__ Si) {
    int r = threadIdx.x;
    float a[16], bI[16];
    #pragma unroll
    for (int j = 0; j < 16; ++j) {
        a[j]  = (r < 16) ? S[r * 16 + j] : 0.f;
        bI[j] = (r < 16 && j == r) ? 1.f : 0.f;
    }
    for (int k = 0; k < 16; ++k) {
        float pa[16], pb[16];
        #pragma unroll
        for (int j = 0; j < 16; ++j) { pa[j] = __shfl(a[j], k); pb[j] = __shfl(bI[j], k); }
        float inv = 1.0f / pa[k];
        if (r == k) {
            #pragma unroll
            for (int j = 0; j < 16; ++j) { a[j] = pa[j] * inv; bI[j] = pb[j] * inv; }
        } else {
            float f = a[k] * inv;
            #pragma unroll
            for (int j = 0; j < 16; ++j) {
                a[j]  = fmaf(-f, pa[j], a[j]);
                bI[j] = fmaf(-f, pb[j], bI[j]);
            }
        }
    }
    if (r < 16)
        #pragma unroll
        for (int j = 0; j < 16; ++j) Si[r * 16 + j] = bI[j];
}

// ---------------- f32 NT GEMM (kept for small ME-dim GEMMs) ----------------
#define TBM 64
#define TBN 64
#define TBK 16

__global__ __launch_bounds__(256) void gemm_nt(
    const float* __restrict__ A, const float* __restrict__ B, float* __restrict__ C,
    int M, int N, int K, int mode, const float* __restrict__ E)
{
    __shared__ float As[TBK][TBM + 4];
    __shared__ float Bs[TBK][TBN + 4];
    const int tid = threadIdx.x;
    const int lk = tid & 15, lm = tid >> 4;
    const int m0 = blockIdx.y * TBM, n0 = blockIdx.x * TBN;
    const int tx = tid & 15, ty = tid >> 4;

    float acc[4][4] = {{0.f,0.f,0.f,0.f},{0.f,0.f,0.f,0.f},{0.f,0.f,0.f,0.f},{0.f,0.f,0.f,0.f}};

    for (int k0 = 0; k0 < K; k0 += TBK) {
        int kk = k0 + lk;
        #pragma unroll
        for (int i = 0; i < 4; ++i) {
            int m = m0 + lm + i * 16;
            As[lk][lm + i * 16] = (m < M && kk < K) ? A[(size_t)m * K + kk] : 0.f;
            int n = n0 + lm + i * 16;
            Bs[lk][lm + i * 16] = (n < N && kk < K) ? B[(size_t)n * K + kk] : 0.f;
        }
        __syncthreads();
        #pragma unroll
        for (int k = 0; k < TBK; ++k) {
            float av[4], bv[4];
            #pragma unroll
            for (int i = 0; i < 4; ++i) av[i] = As[k][ty * 4 + i];
            #pragma unroll
            for (int j = 0; j < 4; ++j) bv[j] = Bs[k][tx * 4 + j];
            #pragma unroll
            for (int i = 0; i < 4; ++i)
                #pragma unroll
                for (int j = 0; j < 4; ++j)
                    acc[i][j] = fmaf(av[i], bv[j], acc[i][j]);
        }
        __syncthreads();
    }

    #pragma unroll
    for (int i = 0; i < 4; ++i) {
        #pragma unroll
        for (int j = 0; j < 4; ++j) {
            int m = m0 + ty * 4 + i, n = n0 + tx * 4 + j;
            if (m >= M || n >= N) continue;
            size_t idx = (size_t)m * N + n;
            float a = acc[i][j];
            if (mode == 0)      C[idx] = a;
            else                C[idx] = E[idx] - a;   // mode 3: W1 = Minv - T1 Y^T
        }
    }
}

// ---------------- split-bf16 MFMA NT GEMM, K fixed = 512 ----------------
// C[m,n] = sum_k A[m,k]*B[n,k] with A,B given as hi/lo bf16 planes [rows][512].
// acc = Ahi*Bhi + Ahi*Blo + Alo*Bhi  (~2^-17 relative accuracy).
// Tile 64x64, 256 threads = 4 waves; wave w owns rows [w*16,w*16+16), 4 col-tiles.
// epi: 0 C=acc (+planes if Chi)            (xW / NS-U / R / Q)
//      1 C=acc+(m==n), planes              (Mm = I + G^T G)
//      2 C=2E-acc, planes                  (Newton-Schulz X')
//      3 C=acc+v1[n]                       (q0 = x R^T + g0)
//      4 planes=min(v1[n],acc), U=0        (ADMM init: t0 = min(h, xG^T), u0=0)
//      5 Gz=acc+E; w=v1[n]-Gz-U; U=relu(-w); planes=v1[n]-|w|   (ADMM step)
//      6 C=acc+E+v1[n]                     (final z = tR + xW1 + zb)
#define LDK 40  // padded LDS k-stride (bf16 elems): 80B rows, 16B aligned, 2-way banks (free)

__global__ __launch_bounds__(256) void mfma_gemm(
    const short* __restrict__ Ahi, const short* __restrict__ Alo,
    const short* __restrict__ Bhi, const short* __restrict__ Blo,
    float* __restrict__ C, short* __restrict__ Chi, short* __restrict__ Clo,
    const float* __restrict__ E, const float* __restrict__ v1,
    float* __restrict__ U, int epi)
{
    __shared__ short Ash[2][64 * LDK];
    __shared__ short Bsh[2][64 * LDK];
    const int tid = threadIdx.x;
    const int wv = tid >> 6, ln = tid & 63;
    const int quad = ln >> 4, lr = ln & 15;
    const int m0 = blockIdx.y * 64, n0 = blockIdx.x * 64;
    const int N = gridDim.x * 64;
    const int tr = tid >> 2, tk = (tid & 3) * 8;  // staging: row tr, k-offset tk

    float4v acc[4];
    #pragma unroll
    for (int ct = 0; ct < 4; ++ct) acc[ct] = (float4v){0.f, 0.f, 0.f, 0.f};

    for (int k0 = 0; k0 < 512; k0 += 32) {
        size_t ga = (size_t)(m0 + tr) * 512 + k0 + tk;
        size_t gb = (size_t)(n0 + tr) * 512 + k0 + tk;
        short8 vah = *(const short8*)(Ahi + ga);
        short8 val = *(const short8*)(Alo + ga);
        short8 vbh = *(const short8*)(Bhi + gb);
        short8 vbl = *(const short8*)(Blo + gb);
        __syncthreads();
        *(short8*)&Ash[0][tr * LDK + tk] = vah;
        *(short8*)&Ash[1][tr * LDK + tk] = val;
        *(short8*)&Bsh[0][tr * LDK + tk] = vbh;
        *(short8*)&Bsh[1][tr * LDK + tk] = vbl;
        __syncthreads();

        // A-frag: A[m = wv*16+lr][k = quad*8 + j]
        short8 ah = *(const short8*)&Ash[0][(wv * 16 + lr) * LDK + quad * 8];
        short8 al = *(const short8*)&Ash[1][(wv * 16 + lr) * LDK + quad * 8];
        #pragma unroll
        for (int ct = 0; ct < 4; ++ct) {
            short8 bh = *(const short8*)&Bsh[0][(ct * 16 + lr) * LDK + quad * 8];
            short8 bl = *(const short8*)&Bsh[1][(ct * 16 + lr) * LDK + quad * 8];
            acc[ct] = __builtin_amdgcn_mfma_f32_16x16x32_bf16(ah, bh, acc[ct], 0, 0, 0);
            acc[ct] = __builtin_amdgcn_mfma_f32_16x16x32_bf16(ah, bl, acc[ct], 0, 0, 0);
            acc[ct] = __builtin_amdgcn_mfma_f32_16x16x32_bf16(al, bh, acc[ct], 0, 0, 0);
        }
    }

    // C/D layout: col = lane&15, row = quad*4 + reg (m89-verified)
    #pragma unroll
    for (int ct = 0; ct < 4; ++ct) {
        #pragma unroll
        for (int r = 0; r < 4; ++r) {
            int m = m0 + wv * 16 + quad * 4 + r;
            int n = n0 + ct * 16 + lr;
            size_t idx = (size_t)m * N + n;
            float a = acc[ct][r];
            if (epi == 0) {
                C[idx] = a;
                if (Chi) split_store(a, Chi, Clo, idx);
            } else if (epi == 1) {
                a += (m == n) ? 1.f : 0.f;
                C[idx] = a;
                split_store(a, Chi, Clo, idx);
            } else if (epi == 2) {
                a = 2.f * E[idx] - a;
                C[idx] = a;
                split_store(a, Chi, Clo, idx);
            } else if (epi == 3) {
                C[idx] = a + v1[n];
            } else if (epi == 4) {
                float t0 = fminf(v1[n], a);
                U[idx] = 0.f;
                split_store(t0, Chi, Clo, idx);
            } else if (epi == 5) {
                float w = v1[n] - (a + E[idx]) - U[idx];
                U[idx] = fmaxf(0.f, -w);
                split_store(v1[n] - fabsf(w), Chi, Clo, idx);
            } else {
                C[idx] = a + E[idx] + v1[n];
            }
        }
    }
}

// ---------------- host launcher ----------------

extern "C" void kernel_launch(void* const* d_in, const int* in_sizes, int n_in,
                              void* d_out, int out_size, void* d_ws, size_t ws_size,
                              hipStream_t stream) {
    const void* c_raw = d_in[0];
    const void* G_raw = d_in[1];
    const void* h_raw = d_in[2];
    const void* A_raw = d_in[3];
    const void* b_raw = d_in[4];

    float* w = (float*)d_ws;
    size_t o = 0;
    auto alloc = [&](size_t n) { float* p = w + o; o += (n + 63) & ~(size_t)63; return p; };

    // f32 buffers
    float* cF  = alloc(BB * NN);
    float* GF  = alloc(MI * NN);
    float* GT  = alloc(NN * MI);
    float* AF  = alloc(ME * NN);
    float* hF  = alloc(MI);
    float* bF  = alloc(ME);
    float* Mm  = alloc(NN * NN);
    float* Xf0 = alloc(NN * NN);
    float* Xf1 = alloc(NN * NN);
    float* Ubf = alloc(NN * NN);   // scratch C for U-gemm / Q-gemm
    float* W1f = alloc(NN * NN);
    float* Rf  = alloc(MI * NN);
    float* RTf = alloc(NN * MI);
    float* Y   = alloc(NN * ME);
    float* YT  = alloc(ME * NN);
    float* T1  = alloc(NN * ME);
    float* Sm  = alloc(ME * ME);
    float* Si  = alloc(ME * ME);
    float* zb  = alloc(NN);
    float* g0  = alloc(MI);
    float* rs  = alloc(NN);
    float* c0s = alloc(16);
    float* dtf = alloc(16);
    float* q0  = alloc(BB * MI);
    float* xW  = alloc(BB * NN);
    float* uB  = alloc(BB * MI);
    float* zf  = alloc(BB * NN);

    // bf16 hi/lo planes (shorts), carved after f32 region
    short* sb = (short*)(w + o);
    size_t so = 0;
    auto allocS = [&](size_t n) { short* p = sb + so; so += (n + 127) & ~(size_t)127; return p; };

    short* GFh = allocS(MI * NN);  short* GFl = allocS(MI * NN);
    short* GTh = allocS(NN * MI);  short* GTl = allocS(NN * MI);
    short* Mmh = allocS(NN * NN);  short* Mml = allocS(NN * NN);
    short* X0h = allocS(NN * NN);  short* X0l = allocS(NN * NN);
    short* X1h = allocS(NN * NN);  short* X1l = allocS(NN * NN);
    short* Uh  = allocS(NN * NN);  short* Ul  = allocS(NN * NN);
    short* W1h = allocS(NN * NN);  short* W1l = allocS(NN * NN);
    short* Rh  = allocS(MI * NN);  short* Rl  = allocS(MI * NN);
    short* RTh = allocS(NN * MI);  short* RTl = allocS(NN * MI);
    short* Qh  = allocS(MI * MI);  short* Ql  = allocS(MI * MI);
    short* xh  = allocS(BB * NN);  short* xl  = allocS(BB * NN);
    short* tAh = allocS(BB * MI);  short* tAl = allocS(BB * MI);
    short* tBh = allocS(BB * MI);  short* tBl = allocS(BB * MI);

    dim3 blk(256);
    auto cdiv = [](int a, int b) { return (a + b - 1) / b; };
    dim3 gSq(8, 8);    // 512x512 outputs
    dim3 gBt(8, 16);   // 1024x512 outputs

    // --- detect dtype, ingest ---
    detect_dtype_k<<<1, 256, 0, stream>>>((const unsigned short*)G_raw, dtf);
    ingest_k<<<cdiv(BB * NN, 256), blk, 0, stream>>>(c_raw, cF, BB * NN, dtf);
    ingest_k<<<cdiv(MI * NN, 256), blk, 0, stream>>>(G_raw, GF, MI * NN, dtf);
    ingest_k<<<cdiv(MI, 256),      blk, 0, stream>>>(h_raw, hF, MI, dtf);
    ingest_k<<<cdiv(ME * NN, 256), blk, 0, stream>>>(A_raw, AF, ME * NN, dtf);
    ingest_k<<<cdiv(ME, 256),      blk, 0, stream>>>(b_raw, bF, ME, dtf);

    // --- splits of G, G^T ---
    transpose512<<<dim3(16, 16), blk, 0, stream>>>(GF, GT);
    split_k<<<cdiv(MI * NN, 256), blk, 0, stream>>>(GF, GFh, GFl, MI * NN);
    split_k<<<cdiv(NN * MI, 256), blk, 0, stream>>>(GT, GTh, GTl, NN * MI);

    // --- M = I + G^T G  (MFMA, epi 1) ---
    mfma_gemm<<<gSq, blk, 0, stream>>>(GTh, GTl, GTh, GTl, Mm, Mmh, Mml, nullptr, nullptr, nullptr, 1);

    // --- Newton-Schulz inverse of M ---
    row_abs_sum_k<<<NN, 64, 0, stream>>>(Mm, rs);
    max_c0_k<<<1, 64, 0, stream>>>(rs, c0s);
    init_X_k<<<cdiv(NN * NN, 256), blk, 0, stream>>>(Xf0, X0h, X0l, c0s);
    float* Xf[2] = {Xf0, Xf1};
    short* Xh[2] = {X0h, X1h};
    short* Xl[2] = {X0l, X1l};
    int cur = 0;
    for (int it = 0; it < NS_ITERS; ++it) {
        int nxt = cur ^ 1;
        // U = X * M
        mfma_gemm<<<gSq, blk, 0, stream>>>(Xh[cur], Xl[cur], Mmh, Mml, Ubf, Uh, Ul,
                                           nullptr, nullptr, nullptr, 0);
        // X' = 2X - U*X
        mfma_gemm<<<gSq, blk, 0, stream>>>(Uh, Ul, Xh[cur], Xl[cur], Xf[nxt], Xh[nxt], Xl[nxt],
                                           Xf[cur], nullptr, nullptr, 2);
        cur = nxt;
    }
    float* Minv = Xf[cur]; short* Mih = Xh[cur]; short* Mil = Xl[cur];

    // --- Schur pieces (small, f32) ---
    gemm_nt<<<dim3(1, 8), blk, 0, stream>>>(Minv, AF, Y,  NN, ME, NN, 0, nullptr);
    gemm_nt<<<dim3(8, 1), blk, 0, stream>>>(AF, Minv, YT, ME, NN, NN, 0, nullptr);
    gemm_nt<<<dim3(1, 1), blk, 0, stream>>>(AF, YT, Sm, ME, ME, NN, 0, nullptr);
    inv16_k<<<1, 64, 0, stream>>>(Sm, Si);
    gemm_nt<<<dim3(1, 8), blk, 0, stream>>>(Y, Si, T1, NN, ME, ME, 0, nullptr);
    gemm_nt<<<dim3(1, 8), blk, 0, stream>>>(T1, bF, zb, NN, 1, ME, 0, nullptr);
    // W1 = Minv - T1 Y^T  (K=16, f32), then split
    gemm_nt<<<gSq, blk, 0, stream>>>(T1, Y, W1f, NN, NN, ME, 3, Minv);
    split_k<<<cdiv(NN * NN, 256), blk, 0, stream>>>(W1f, W1h, W1l, NN * NN);

    // --- R = G W1 (MFMA), RT, Q = R G^T (MFMA) ---
    mfma_gemm<<<gSq, blk, 0, stream>>>(GFh, GFl, W1h, W1l, Rf, Rh, Rl, nullptr, nullptr, nullptr, 0);
    transpose512<<<dim3(16, 16), blk, 0, stream>>>(Rf, RTf);
    split_k<<<cdiv(NN * MI, 256), blk, 0, stream>>>(RTf, RTh, RTl, NN * MI);
    mfma_gemm<<<gSq, blk, 0, stream>>>(Rh, Rl, GFh, GFl, Ubf, Qh, Ql, nullptr, nullptr, nullptr, 0);
    gemm_nt<<<dim3(1, 8), blk, 0, stream>>>(GF, zb, g0, MI, 1, NN, 0, nullptr);

    // --- 4 projections ---
    split_k<<<cdiv(BB * NN, 256), blk, 0, stream>>>(cF, xh, xl, BB * NN);  // x0 = c
    for (int p = 0; p < 4; ++p) {
        // t0 = min(h, x G^T), u0 = 0  (epi 4)
        mfma_gemm<<<gBt, blk, 0, stream>>>(xh, xl, GFh, GFl, Ubf, tAh, tAl,
                                           nullptr, hF, uB, 4);
        // q0 = x R^T + g0  (epi 3)
        mfma_gemm<<<gBt, blk, 0, stream>>>(xh, xl, Rh, Rl, q0, nullptr, nullptr,
                                           nullptr, g0, nullptr, 3);
        // xW = x W1  (epi 0, no planes)
        mfma_gemm<<<gBt, blk, 0, stream>>>(xh, xl, W1h, W1l, xW, nullptr, nullptr,
                                           nullptr, nullptr, nullptr, 0);

        short* th[2] = {tAh, tBh};
        short* tl[2] = {tAl, tBl};
        int tc = 0;
        for (int it = 0; it < ADMM_IT; ++it) {
            int tn = tc ^ 1;
            mfma_gemm<<<gBt, blk, 0, stream>>>(th[tc], tl[tc], Qh, Ql, Ubf, th[tn], tl[tn],
                                               q0, hF, uB, 5);
            tc = tn;
        }
        // z = t R + x W1 + zb  (epi 6)
        mfma_gemm<<<gBt, blk, 0, stream>>>(th[tc], tl[tc], RTh, RTl, zf, nullptr, nullptr,
                                           xW, zb, nullptr, 6);

        if (p < 3) {
            pgd_split_k<<<cdiv(BB * NN, 256), blk, 0, stream>>>(zf, cF, xh, xl, BB * NN);
        } else {
            emit_k<<<cdiv(BB * NN, 256), blk, 0, stream>>>(zf, d_out, BB * NN, dtf);
        }
    }
}

// Round 5
// 1150.449 us; speedup vs baseline: 3.9828x; 1.5994x over previous
//
#include <hip/hip_runtime.h>
#include <hip/hip_bf16.h>

// Problem constants (fixed by the reference)
#define BB 1024   // batch
#define NN 512    // variable dim
#define MI 512    // inequality count
#define ME 16     // equality count
#define ALPHA 0.05f
#define NS_ITERS 8   // Gershgorin c0 -> r0~0.9; 0.9^(2^8)=5e-13: converged
#define ADMM_IT 15

typedef __attribute__((ext_vector_type(8))) short short8;   // 8 bf16 = 4 VGPRs
typedef __attribute__((ext_vector_type(4))) float float4v;  // MFMA accumulator

__device__ inline short f2bf(float v) {
    __hip_bfloat16 b = __float2bfloat16(v);
    return *reinterpret_cast<short*>(&b);
}
__device__ inline float bf2f(short s) {
    __hip_bfloat16 b = *reinterpret_cast<__hip_bfloat16*>(&s);
    return __bfloat162float(b);
}
// split f32 -> hi/lo bf16 planes (hi + lo carries ~16 mantissa bits)
__device__ inline void split_store(float v, short* __restrict__ hi, short* __restrict__ lo, size_t idx) {
    short h = f2bf(v);
    hi[idx] = h;
    lo[idx] = f2bf(v - bf2f(h));
}

// ---------------- dtype auto-detect (bf16 vs f32 inputs) ----------------
__global__ void detect_dtype_k(const unsigned short* __restrict__ g_raw,
                               float* __restrict__ flag) {
    __shared__ int cnt;
    int tid = threadIdx.x;
    if (tid == 0) cnt = 0;
    __syncthreads();
    int local = 0;
    for (int i = tid; i < 8192; i += 256) {
        int e = (g_raw[i] >> 7) & 0xFF;
        if (e >= 0x83) local++;   // |v|>=16, inf, or NaN under bf16 view
    }
    atomicAdd(&cnt, local);
    __syncthreads();
    if (tid == 0) flag[0] = (cnt < 64) ? 1.0f : 0.0f;  // 1 => bf16 inputs
}

// ---------------- elementwise ----------------
__global__ void ingest_k(const void* __restrict__ src, float* __restrict__ dst,
                         int n, const float* __restrict__ flag) {
    int i = blockIdx.x * 256 + threadIdx.x;
    if (i >= n) return;
    if (flag[0] > 0.5f) dst[i] = __bfloat162float(((const __hip_bfloat16*)src)[i]);
    else                dst[i] = ((const float*)src)[i];
}

__global__ void emit_k(const float* __restrict__ src, void* __restrict__ dst,
                       int n, const float* __restrict__ flag) {
    int i = blockIdx.x * 256 + threadIdx.x;
    if (i >= n) return;
    if (flag[0] > 0.5f) ((__hip_bfloat16*)dst)[i] = __float2bfloat16(src[i]);
    else                ((float*)dst)[i] = src[i];
}

__global__ void split_k(const float* __restrict__ src, short* __restrict__ hi,
                        short* __restrict__ lo, int n) {
    int i = blockIdx.x * 256 + threadIdx.x;
    if (i < n) split_store(src[i], hi, lo, i);
}

__global__ void pgd_split_k(const float* __restrict__ z, const float* __restrict__ c,
                            short* __restrict__ xhi, short* __restrict__ xlo, int n) {
    int i = blockIdx.x * 256 + threadIdx.x;
    if (i < n) split_store((1.0f - ALPHA) * z[i] + ALPHA * c[i], xhi, xlo, i);
}

// transpose 512x512
__global__ void transpose512(const float* __restrict__ src, float* __restrict__ dst) {
    __shared__ float t[32][33];
    int bx = blockIdx.x * 32, by = blockIdx.y * 32;
    int tx = threadIdx.x & 31, ty0 = threadIdx.x >> 5;
    for (int i = ty0; i < 32; i += 8) t[i][tx] = src[(by + i) * NN + bx + tx];
    __syncthreads();
    for (int i = ty0; i < 32; i += 8) dst[(bx + i) * NN + by + tx] = t[tx][i];
}

__global__ void row_abs_sum_k(const float* __restrict__ Mm, float* __restrict__ rs) {
    int row = blockIdx.x, lane = threadIdx.x;
    float s = 0.f;
    for (int j = lane; j < NN; j += 64) s += fabsf(Mm[row * NN + j]);
    for (int off = 32; off; off >>= 1) s += __shfl_down(s, off);
    if (lane == 0) rs[row] = s;
}

__global__ void max_c0_k(const float* __restrict__ rs, float* __restrict__ c0s) {
    int lane = threadIdx.x;
    float m = 0.f;
    for (int i = lane; i < NN; i += 64) m = fmaxf(m, rs[i]);
    for (int off = 32; off; off >>= 1) m = fmaxf(m, __shfl_down(m, off));
    if (lane == 0) c0s[0] = 2.0f / (1.0f + m);
}

__global__ void init_X_k(float* __restrict__ X, short* __restrict__ Xhi,
                         short* __restrict__ Xlo, const float* __restrict__ c0s) {
    int idx = blockIdx.x * 256 + threadIdx.x;
    if (idx < NN * NN) {
        int i = idx / NN, j = idx - i * NN;
        float v = (i == j) ? c0s[0] : 0.f;
        X[idx] = v;
        split_store(v, Xhi, Xlo, idx);
    }
}

// 16x16 inverse via Gauss-Jordan, one wave
__global__ void inv16_k(const float* __restrict__ S, float* __restrict__ Si) {
    int r = threadIdx.x;
    float a[16], bI[16];
    #pragma unroll
    for (int j = 0; j < 16; ++j) {
        a[j]  = (r < 16) ? S[r * 16 + j] : 0.f;
        bI[j] = (r < 16 && j == r) ? 1.f : 0.f;
    }
    for (int k = 0; k < 16; ++k) {
        float pa[16], pb[16];
        #pragma unroll
        for (int j = 0; j < 16; ++j) { pa[j] = __shfl(a[j], k); pb[j] = __shfl(bI[j], k); }
        float inv = 1.0f / pa[k];
        if (r == k) {
            #pragma unroll
            for (int j = 0; j < 16; ++j) { a[j] = pa[j] * inv; bI[j] = pb[j] * inv; }
        } else {
            float f = a[k] * inv;
            #pragma unroll
            for (int j = 0; j < 16; ++j) {
                a[j]  = fmaf(-f, pa[j], a[j]);
                bI[j] = fmaf(-f, pb[j], bI[j]);
            }
        }
    }
    if (r < 16)
        #pragma unroll
        for (int j = 0; j < 16; ++j) Si[r * 16 + j] = bI[j];
}

// ---------------- skinny ME-dim kernels (replace serial f32 GEMMs) ----------------
// Y[m][j] = sum_k Minv[m][k] * AF[j][k]   (512x16, K=512); one block per m, wave per 4 j's
__global__ void Y_k(const float* __restrict__ Minv, const float* __restrict__ AF,
                    float* __restrict__ Y) {
    int m = blockIdx.x;
    int wv = threadIdx.x >> 6, lane = threadIdx.x & 63;
    float mv[8];
    #pragma unroll
    for (int i = 0; i < 8; ++i) mv[i] = Minv[m * 512 + lane + i * 64];
    #pragma unroll
    for (int jj = 0; jj < 4; ++jj) {
        int j = wv * 4 + jj;
        float s = 0.f;
        #pragma unroll
        for (int i = 0; i < 8; ++i) s += mv[i] * AF[j * 512 + lane + i * 64];
        for (int off = 32; off; off >>= 1) s += __shfl_down(s, off);
        if (lane == 0) Y[m * 16 + j] = s;
    }
}

// Sm[i][j] = sum_k AF[i][k] * Y[k][j]   (16x16, K=512); one block, thread per output
__global__ void Sm_k(const float* __restrict__ AF, const float* __restrict__ Y,
                     float* __restrict__ Sm) {
    int i = threadIdx.x >> 4, j = threadIdx.x & 15;
    float s = 0.f;
    #pragma unroll 8
    for (int k = 0; k < 512; ++k) s += AF[i * 512 + k] * Y[k * 16 + j];
    Sm[i * 16 + j] = s;
}

// T1 = Y*Si (512x16, K=16) and zb = T1 @ b (512)
__global__ void T1zb_k(const float* __restrict__ Y, const float* __restrict__ Si,
                       const float* __restrict__ bF, float* __restrict__ T1,
                       float* __restrict__ zb) {
    int m = blockIdx.x * 16 + (threadIdx.x >> 4), j = threadIdx.x & 15;
    float s = 0.f;
    #pragma unroll
    for (int k = 0; k < 16; ++k) s += Y[m * 16 + k] * Si[k * 16 + j];
    T1[m * 16 + j] = s;
    float v = s * bF[j];
    v += __shfl_down(v, 8); v += __shfl_down(v, 4);
    v += __shfl_down(v, 2); v += __shfl_down(v, 1);
    if (j == 0) zb[m] = v;
}

// W1 = Minv - T1 Y^T (512x512, K=16) + hi/lo planes
__global__ void W1_k(const float* __restrict__ Minv, const float* __restrict__ T1,
                     const float* __restrict__ Y, float* __restrict__ W1,
                     short* __restrict__ W1h, short* __restrict__ W1l) {
    int idx = blockIdx.x * 256 + threadIdx.x;
    int m = idx >> 9, n = idx & 511;
    float s = Minv[idx];
    #pragma unroll
    for (int k = 0; k < 16; ++k) s -= T1[m * 16 + k] * Y[n * 16 + k];
    W1[idx] = s;
    split_store(s, W1h, W1l, idx);
}

// g0[m] = sum_k G[m][k] * zb[k]  (512 dots of 512); wave per row
__global__ void g0_k(const float* __restrict__ GF, const float* __restrict__ zb,
                     float* __restrict__ g0) {
    int m = blockIdx.x * 4 + (threadIdx.x >> 6);
    int lane = threadIdx.x & 63;
    float s = 0.f;
    #pragma unroll
    for (int i = 0; i < 8; ++i) s += GF[m * 512 + lane + i * 64] * zb[lane + i * 64];
    for (int off = 32; off; off >>= 1) s += __shfl_down(s, off);
    if (lane == 0) g0[m] = s;
}

// ---------------- split-bf16 MFMA NT GEMM, K fixed = 512 ----------------
// C[m,n] = sum_k A[m,k]*B[n,k]; A,B as hi/lo bf16 planes. acc = hh + hl + lh.
// Template RG = row-groups: tile (RG*16) x 64, 256 threads (4 waves).
//   RG=2: batch GEMMs, grid (8, 32) = 256 blocks for 1024x512
//   RG=1: square GEMMs, grid (8, 32) = 256 blocks for 512x512
// Register-prefetch of next k-chunk issued before the MFMA block (latency hiding).
// epi: 0 C=acc (+planes if Chi)      1 C=acc+(m==n), planes
//      2 C=2E-acc, planes            3 C=acc+v1[n]
//      4 planes=min(v1[n],acc), U=0  5 ADMM step (see round-4 derivation)
//      6 C=acc+E+v1[n]
#define LDK 40

template<int RG>
__global__ __launch_bounds__(256) void mfma_gemm(
    const short* __restrict__ Ahi, const short* __restrict__ Alo,
    const short* __restrict__ Bhi, const short* __restrict__ Blo,
    float* __restrict__ C, short* __restrict__ Chi, short* __restrict__ Clo,
    const float* __restrict__ E, const float* __restrict__ v1,
    float* __restrict__ U, int epi)
{
    constexpr int TM = RG * 16;
    __shared__ short Ash[2][TM * LDK];
    __shared__ short Bsh[2][64 * LDK];
    const int tid = threadIdx.x;
    const int wv = tid >> 6, ln = tid & 63;
    const int quad = ln >> 4, lr = ln & 15;
    const int row_grp = wv % RG;          // RG=1 -> 0
    const int col_grp = wv / RG;          // spans 16*RG cols each
    const int m0 = blockIdx.y * TM, n0 = blockIdx.x * 64;
    const int N = gridDim.x * 64;

    // staging decode: A vecs = TM*8 (row,oct,plane), B vecs = 512 (2 per thread)
    const int aslot = tid & (TM * 4 - 1);
    const int apl   = (tid < TM * 8) ? (tid / (TM * 4)) : 0;
    const int arow  = aslot >> 2, aoct = aslot & 3;
    const int brow  = tid >> 2,   boct = tid & 3;
    const short* Apl = apl ? Alo : Ahi;

    float4v acc[RG];
    #pragma unroll
    for (int ct = 0; ct < RG; ++ct) acc[ct] = (float4v){0.f, 0.f, 0.f, 0.f};

    short8 ra, rb0, rb1;
    if (tid < TM * 8) ra = *(const short8*)(Apl + (size_t)(m0 + arow) * 512 + aoct * 8);
    rb0 = *(const short8*)(Bhi + (size_t)(n0 + brow) * 512 + boct * 8);
    rb1 = *(const short8*)(Blo + (size_t)(n0 + brow) * 512 + boct * 8);

    for (int k0 = 0; k0 < 512; k0 += 32) {
        if (k0) __syncthreads();
        if (tid < TM * 8) *(short8*)&Ash[apl][arow * LDK + aoct * 8] = ra;
        *(short8*)&Bsh[0][brow * LDK + boct * 8] = rb0;
        *(short8*)&Bsh[1][brow * LDK + boct * 8] = rb1;
        __syncthreads();
        if (k0 + 32 < 512) {
            int kn = k0 + 32;
            if (tid < TM * 8) ra = *(const short8*)(Apl + (size_t)(m0 + arow) * 512 + kn + aoct * 8);
            rb0 = *(const short8*)(Bhi + (size_t)(n0 + brow) * 512 + kn + boct * 8);
            rb1 = *(const short8*)(Blo + (size_t)(n0 + brow) * 512 + kn + boct * 8);
        }
        short8 ah = *(const short8*)&Ash[0][(row_grp * 16 + lr) * LDK + quad * 8];
        short8 al = *(const short8*)&Ash[1][(row_grp * 16 + lr) * LDK + quad * 8];
        #pragma unroll
        for (int ct = 0; ct < RG; ++ct) {
            int bcol = col_grp * (16 * RG) + ct * 16 + lr;
            short8 bh = *(const short8*)&Bsh[0][bcol * LDK + quad * 8];
            short8 bl = *(const short8*)&Bsh[1][bcol * LDK + quad * 8];
            acc[ct] = __builtin_amdgcn_mfma_f32_16x16x32_bf16(ah, bh, acc[ct], 0, 0, 0);
            acc[ct] = __builtin_amdgcn_mfma_f32_16x16x32_bf16(ah, bl, acc[ct], 0, 0, 0);
            acc[ct] = __builtin_amdgcn_mfma_f32_16x16x32_bf16(al, bh, acc[ct], 0, 0, 0);
        }
    }

    // C/D layout: col = lane&15, row = quad*4 + reg (m89-verified)
    #pragma unroll
    for (int ct = 0; ct < RG; ++ct) {
        #pragma unroll
        for (int r = 0; r < 4; ++r) {
            int m = m0 + row_grp * 16 + quad * 4 + r;
            int n = n0 + col_grp * (16 * RG) + ct * 16 + lr;
            size_t idx = (size_t)m * N + n;
            float a = acc[ct][r];
            if (epi == 0) {
                C[idx] = a;
                if (Chi) split_store(a, Chi, Clo, idx);
            } else if (epi == 1) {
                a += (m == n) ? 1.f : 0.f;
                C[idx] = a;
                split_store(a, Chi, Clo, idx);
            } else if (epi == 2) {
                a = 2.f * E[idx] - a;
                C[idx] = a;
                split_store(a, Chi, Clo, idx);
            } else if (epi == 3) {
                C[idx] = a + v1[n];
            } else if (epi == 4) {
                float t0 = fminf(v1[n], a);
                U[idx] = 0.f;
                split_store(t0, Chi, Clo, idx);
            } else if (epi == 5) {
                float w = v1[n] - (a + E[idx]) - U[idx];
                U[idx] = fmaxf(0.f, -w);
                split_store(v1[n] - fabsf(w), Chi, Clo, idx);
            } else {
                C[idx] = a + E[idx] + v1[n];
            }
        }
    }
}

// ---------------- host launcher ----------------

extern "C" void kernel_launch(void* const* d_in, const int* in_sizes, int n_in,
                              void* d_out, int out_size, void* d_ws, size_t ws_size,
                              hipStream_t stream) {
    const void* c_raw = d_in[0];
    const void* G_raw = d_in[1];
    const void* h_raw = d_in[2];
    const void* A_raw = d_in[3];
    const void* b_raw = d_in[4];

    float* w = (float*)d_ws;
    size_t o = 0;
    auto alloc = [&](size_t n) { float* p = w + o; o += (n + 63) & ~(size_t)63; return p; };

    // f32 buffers
    float* cF  = alloc(BB * NN);
    float* GF  = alloc(MI * NN);
    float* GT  = alloc(NN * MI);
    float* AF  = alloc(ME * NN);
    float* hF  = alloc(MI);
    float* bF  = alloc(ME);
    float* Mm  = alloc(NN * NN);
    float* Xf0 = alloc(NN * NN);
    float* Xf1 = alloc(NN * NN);
    float* Ubf = alloc(NN * NN);
    float* W1f = alloc(NN * NN);
    float* Rf  = alloc(MI * NN);
    float* RTf = alloc(NN * MI);
    float* Y   = alloc(NN * ME);
    float* T1  = alloc(NN * ME);
    float* Sm  = alloc(ME * ME);
    float* Si  = alloc(ME * ME);
    float* zb  = alloc(NN);
    float* g0  = alloc(MI);
    float* rs  = alloc(NN);
    float* c0s = alloc(16);
    float* dtf = alloc(16);
    float* q0  = alloc(BB * MI);
    float* xW  = alloc(BB * NN);
    float* uB  = alloc(BB * MI);
    float* zf  = alloc(BB * NN);

    // bf16 hi/lo planes
    short* sb = (short*)(w + o);
    size_t so = 0;
    auto allocS = [&](size_t n) { short* p = sb + so; so += (n + 127) & ~(size_t)127; return p; };

    short* GFh = allocS(MI * NN);  short* GFl = allocS(MI * NN);
    short* GTh = allocS(NN * MI);  short* GTl = allocS(NN * MI);
    short* Mmh = allocS(NN * NN);  short* Mml = allocS(NN * NN);
    short* X0h = allocS(NN * NN);  short* X0l = allocS(NN * NN);
    short* X1h = allocS(NN * NN);  short* X1l = allocS(NN * NN);
    short* Uh  = allocS(NN * NN);  short* Ul  = allocS(NN * NN);
    short* W1h = allocS(NN * NN);  short* W1l = allocS(NN * NN);
    short* Rh  = allocS(MI * NN);  short* Rl  = allocS(MI * NN);
    short* RTh = allocS(NN * MI);  short* RTl = allocS(NN * MI);
    short* Qh  = allocS(MI * MI);  short* Ql  = allocS(MI * MI);
    short* xh  = allocS(BB * NN);  short* xl  = allocS(BB * NN);
    short* tAh = allocS(BB * MI);  short* tAl = allocS(BB * MI);
    short* tBh = allocS(BB * MI);  short* tBl = allocS(BB * MI);

    dim3 blk(256);
    auto cdiv = [](int a, int b) { return (a + b - 1) / b; };
    dim3 gSq(8, 32);   // square: RG=1, 512x512 -> 256 blocks
    dim3 gBt(8, 32);   // batch:  RG=2, 1024x512 -> 256 blocks

    // --- detect dtype, ingest ---
    detect_dtype_k<<<1, 256, 0, stream>>>((const unsigned short*)G_raw, dtf);
    ingest_k<<<cdiv(BB * NN, 256), blk, 0, stream>>>(c_raw, cF, BB * NN, dtf);
    ingest_k<<<cdiv(MI * NN, 256), blk, 0, stream>>>(G_raw, GF, MI * NN, dtf);
    ingest_k<<<cdiv(MI, 256),      blk, 0, stream>>>(h_raw, hF, MI, dtf);
    ingest_k<<<cdiv(ME * NN, 256), blk, 0, stream>>>(A_raw, AF, ME * NN, dtf);
    ingest_k<<<cdiv(ME, 256),      blk, 0, stream>>>(b_raw, bF, ME, dtf);

    // --- splits of G, G^T ---
    transpose512<<<dim3(16, 16), blk, 0, stream>>>(GF, GT);
    split_k<<<cdiv(MI * NN, 256), blk, 0, stream>>>(GF, GFh, GFl, MI * NN);
    split_k<<<cdiv(NN * MI, 256), blk, 0, stream>>>(GT, GTh, GTl, NN * MI);

    // --- M = I + G^T G ---
    mfma_gemm<1><<<gSq, blk, 0, stream>>>(GTh, GTl, GTh, GTl, Mm, Mmh, Mml,
                                          nullptr, nullptr, nullptr, 1);

    // --- Newton-Schulz inverse of M ---
    row_abs_sum_k<<<NN, 64, 0, stream>>>(Mm, rs);
    max_c0_k<<<1, 64, 0, stream>>>(rs, c0s);
    init_X_k<<<cdiv(NN * NN, 256), blk, 0, stream>>>(Xf0, X0h, X0l, c0s);
    float* Xf[2] = {Xf0, Xf1};
    short* Xh[2] = {X0h, X1h};
    short* Xl[2] = {X0l, X1l};
    int cur = 0;
    for (int it = 0; it < NS_ITERS; ++it) {
        int nxt = cur ^ 1;
        mfma_gemm<1><<<gSq, blk, 0, stream>>>(Xh[cur], Xl[cur], Mmh, Mml, Ubf, Uh, Ul,
                                              nullptr, nullptr, nullptr, 0);
        mfma_gemm<1><<<gSq, blk, 0, stream>>>(Uh, Ul, Xh[cur], Xl[cur], Xf[nxt], Xh[nxt], Xl[nxt],
                                              Xf[cur], nullptr, nullptr, 2);
        cur = nxt;
    }
    float* Minv = Xf[cur];

    // --- Schur pieces (skinny kernels; Minv & W1 symmetric => YT = Y^T) ---
    Y_k<<<NN, blk, 0, stream>>>(Minv, AF, Y);
    Sm_k<<<1, blk, 0, stream>>>(AF, Y, Sm);
    inv16_k<<<1, 64, 0, stream>>>(Sm, Si);
    T1zb_k<<<NN / 16, blk, 0, stream>>>(Y, Si, bF, T1, zb);
    W1_k<<<NN * NN / 256, blk, 0, stream>>>(Minv, T1, Y, W1f, W1h, W1l);

    // --- R = G W1, RT, Q = R G^T, g0 = G zb ---
    mfma_gemm<1><<<gSq, blk, 0, stream>>>(GFh, GFl, W1h, W1l, Rf, Rh, Rl,
                                          nullptr, nullptr, nullptr, 0);
    transpose512<<<dim3(16, 16), blk, 0, stream>>>(Rf, RTf);
    split_k<<<cdiv(NN * MI, 256), blk, 0, stream>>>(RTf, RTh, RTl, NN * MI);
    mfma_gemm<1><<<gSq, blk, 0, stream>>>(Rh, Rl, GFh, GFl, Ubf, Qh, Ql,
                                          nullptr, nullptr, nullptr, 0);
    g0_k<<<NN / 4, blk, 0, stream>>>(GF, zb, g0);

    // --- 4 projections ---
    split_k<<<cdiv(BB * NN, 256), blk, 0, stream>>>(cF, xh, xl, BB * NN);  // x0 = c
    for (int p = 0; p < 4; ++p) {
        // t0 = min(h, x G^T), u0 = 0  (epi 4)
        mfma_gemm<2><<<gBt, blk, 0, stream>>>(xh, xl, GFh, GFl, Ubf, tAh, tAl,
                                              nullptr, hF, uB, 4);
        // q0 = x R^T + g0  (epi 3)
        mfma_gemm<2><<<gBt, blk, 0, stream>>>(xh, xl, Rh, Rl, q0, nullptr, nullptr,
                                              nullptr, g0, nullptr, 3);
        // xW = x W1  (epi 0)
        mfma_gemm<2><<<gBt, blk, 0, stream>>>(xh, xl, W1h, W1l, xW, nullptr, nullptr,
                                              nullptr, nullptr, nullptr, 0);

        short* th[2] = {tAh, tBh};
        short* tl[2] = {tAl, tBl};
        int tc = 0;
        for (int it = 0; it < ADMM_IT; ++it) {
            int tn = tc ^ 1;
            mfma_gemm<2><<<gBt, blk, 0, stream>>>(th[tc], tl[tc], Qh, Ql, Ubf, th[tn], tl[tn],
                                                  q0, hF, uB, 5);
            tc = tn;
        }
        // z = t R + x W1 + zb  (epi 6)
        mfma_gemm<2><<<gBt, blk, 0, stream>>>(th[tc], tl[tc], RTh, RTl, zf, nullptr, nullptr,
                                              xW, zb, nullptr, 6);

        if (p < 3) {
            pgd_split_k<<<cdiv(BB * NN, 256), blk, 0, stream>>>(zf, cF, xh, xl, BB * NN);
        } else {
            emit_k<<<cdiv(BB * NN, 256), blk, 0, stream>>>(zf, d_out, BB * NN, dtf);
        }
    }
}

// Round 6
// 897.001 us; speedup vs baseline: 5.1082x; 1.2826x over previous
//
#include <hip/hip_runtime.h>
#include <hip/hip_bf16.h>

// Problem constants (fixed by the reference)
#define BB 1024
#define NN 512
#define MI 512
#define ME 16
#define ALPHA 0.05f
#define NS_ITERS 8   // Gershgorin c0 -> r0~0.9; 0.9^256 ~ 7e-12: converged
#define ADMM_IT 15

typedef __attribute__((ext_vector_type(8))) short short8;
typedef __attribute__((ext_vector_type(4))) float float4v;

__device__ inline short f2bf(float v) {
    __hip_bfloat16 b = __float2bfloat16(v);
    return *reinterpret_cast<short*>(&b);
}
__device__ inline float bf2f(short s) {
    __hip_bfloat16 b = *reinterpret_cast<__hip_bfloat16*>(&s);
    return __bfloat162float(b);
}
__device__ inline void split_store(float v, short* __restrict__ hi, short* __restrict__ lo, size_t idx) {
    short h = f2bf(v);
    hi[idx] = h;
    lo[idx] = f2bf(v - bf2f(h));
}

// ---------------- dtype auto-detect ----------------
__global__ void detect_dtype_k(const unsigned short* __restrict__ g_raw,
                               float* __restrict__ flag) {
    __shared__ int cnt;
    int tid = threadIdx.x;
    if (tid == 0) cnt = 0;
    __syncthreads();
    int local = 0;
    for (int i = tid; i < 8192; i += 256) {
        int e = (g_raw[i] >> 7) & 0xFF;
        if (e >= 0x83) local++;
    }
    atomicAdd(&cnt, local);
    __syncthreads();
    if (tid == 0) flag[0] = (cnt < 64) ? 1.0f : 0.0f;  // 1 => bf16 inputs
}

// ---------------- fused ingest: all 5 inputs + c/G splits ----------------
__global__ void ingest_all_k(const void* __restrict__ c_raw, const void* __restrict__ G_raw,
                             const void* __restrict__ h_raw, const void* __restrict__ A_raw,
                             const void* __restrict__ b_raw,
                             float* __restrict__ cF, short* __restrict__ xh, short* __restrict__ xl,
                             float* __restrict__ GF, short* __restrict__ GFh, short* __restrict__ GFl,
                             float* __restrict__ hF, float* __restrict__ AF, float* __restrict__ bF,
                             const float* __restrict__ flag) {
    int i = blockIdx.x * 256 + threadIdx.x;
    bool isbf = flag[0] > 0.5f;
    #define RD(p, idx) (isbf ? __bfloat162float(((const __hip_bfloat16*)(p))[idx]) : ((const float*)(p))[idx])
    if (i < BB * NN) { float v = RD(c_raw, i); cF[i] = v; split_store(v, xh, xl, i); }
    if (i < MI * NN) { float v = RD(G_raw, i); GF[i] = v; split_store(v, GFh, GFl, i); }
    if (i < MI)      hF[i] = RD(h_raw, i);
    if (i < ME * NN) AF[i] = RD(A_raw, i);
    if (i < ME)      bF[i] = RD(b_raw, i);
    #undef RD
}

// transpose 512x512 f32 -> bf16 hi/lo planes
__global__ void transpose_split_k(const float* __restrict__ src,
                                  short* __restrict__ dh, short* __restrict__ dl) {
    __shared__ float t[32][33];
    int bx = blockIdx.x * 32, by = blockIdx.y * 32;
    int tx = threadIdx.x & 31, ty0 = threadIdx.x >> 5;
    for (int i = ty0; i < 32; i += 8) t[i][tx] = src[(by + i) * 512 + bx + tx];
    __syncthreads();
    for (int i = ty0; i < 32; i += 8)
        split_store(t[tx][i], dh, dl, (size_t)(bx + i) * 512 + by + tx);
}

__global__ void row_abs_sum_k(const float* __restrict__ Mm, float* __restrict__ rs) {
    int row = blockIdx.x, lane = threadIdx.x;
    float s = 0.f;
    for (int j = lane; j < NN; j += 64) s += fabsf(Mm[row * NN + j]);
    for (int off = 32; off; off >>= 1) s += __shfl_down(s, off);
    if (lane == 0) rs[row] = s;
}

__global__ void max_c0_k(const float* __restrict__ rs, float* __restrict__ c0s) {
    int lane = threadIdx.x;
    float m = 0.f;
    for (int i = lane; i < NN; i += 64) m = fmaxf(m, rs[i]);
    for (int off = 32; off; off >>= 1) m = fmaxf(m, __shfl_down(m, off));
    if (lane == 0) c0s[0] = 2.0f / (1.0f + m);
}

__global__ void init_X_k(float* __restrict__ X, short* __restrict__ Xhi,
                         short* __restrict__ Xlo, const float* __restrict__ c0s) {
    int idx = blockIdx.x * 256 + threadIdx.x;
    if (idx < NN * NN) {
        int i = idx / NN, j = idx - i * NN;
        float v = (i == j) ? c0s[0] : 0.f;
        X[idx] = v;
        split_store(v, Xhi, Xlo, idx);
    }
}

__global__ void inv16_k(const float* __restrict__ S, float* __restrict__ Si) {
    int r = threadIdx.x;
    float a[16], bI[16];
    #pragma unroll
    for (int j = 0; j < 16; ++j) {
        a[j]  = (r < 16) ? S[r * 16 + j] : 0.f;
        bI[j] = (r < 16 && j == r) ? 1.f : 0.f;
    }
    for (int k = 0; k < 16; ++k) {
        float pa[16], pb[16];
        #pragma unroll
        for (int j = 0; j < 16; ++j) { pa[j] = __shfl(a[j], k); pb[j] = __shfl(bI[j], k); }
        float inv = 1.0f / pa[k];
        if (r == k) {
            #pragma unroll
            for (int j = 0; j < 16; ++j) { a[j] = pa[j] * inv; bI[j] = pb[j] * inv; }
        } else {
            float f = a[k] * inv;
            #pragma unroll
            for (int j = 0; j < 16; ++j) {
                a[j]  = fmaf(-f, pa[j], a[j]);
                bI[j] = fmaf(-f, pb[j], bI[j]);
            }
        }
    }
    if (r < 16)
        #pragma unroll
        for (int j = 0; j < 16; ++j) Si[r * 16 + j] = bI[j];
}

// ---------------- skinny ME-dim kernels ----------------
__global__ void Y_k(const float* __restrict__ Minv, const float* __restrict__ AF,
                    float* __restrict__ Y) {
    int m = blockIdx.x;
    int wv = threadIdx.x >> 6, lane = threadIdx.x & 63;
    float mv[8];
    #pragma unroll
    for (int i = 0; i < 8; ++i) mv[i] = Minv[m * 512 + lane + i * 64];
    #pragma unroll
    for (int jj = 0; jj < 4; ++jj) {
        int j = wv * 4 + jj;
        float s = 0.f;
        #pragma unroll
        for (int i = 0; i < 8; ++i) s += mv[i] * AF[j * 512 + lane + i * 64];
        for (int off = 32; off; off >>= 1) s += __shfl_down(s, off);
        if (lane == 0) Y[m * 16 + j] = s;
    }
}

__global__ void Sm_k(const float* __restrict__ AF, const float* __restrict__ Y,
                     float* __restrict__ Sm) {
    int i = threadIdx.x >> 4, j = threadIdx.x & 15;
    float s = 0.f;
    #pragma unroll 8
    for (int k = 0; k < 512; ++k) s += AF[i * 512 + k] * Y[k * 16 + j];
    Sm[i * 16 + j] = s;
}

__global__ void T1zb_k(const float* __restrict__ Y, const float* __restrict__ Si,
                       const float* __restrict__ bF, float* __restrict__ T1,
                       float* __restrict__ zb) {
    int m = blockIdx.x * 16 + (threadIdx.x >> 4), j = threadIdx.x & 15;
    float s = 0.f;
    #pragma unroll
    for (int k = 0; k < 16; ++k) s += Y[m * 16 + k] * Si[k * 16 + j];
    T1[m * 16 + j] = s;
    float v = s * bF[j];
    v += __shfl_down(v, 8); v += __shfl_down(v, 4);
    v += __shfl_down(v, 2); v += __shfl_down(v, 1);
    if (j == 0) zb[m] = v;
}

// W1 = Minv - T1 Y^T -> planes only (into Bcat W1 slice)
__global__ void W1_k(const float* __restrict__ Minv, const float* __restrict__ T1,
                     const float* __restrict__ Y,
                     short* __restrict__ W1h, short* __restrict__ W1l) {
    int idx = blockIdx.x * 256 + threadIdx.x;
    int m = idx >> 9, n = idx & 511;
    float s = Minv[idx];
    #pragma unroll
    for (int k = 0; k < 16; ++k) s -= T1[m * 16 + k] * Y[n * 16 + k];
    split_store(s, W1h, W1l, idx);
}

__global__ void g0_k(const float* __restrict__ GF, const float* __restrict__ zb,
                     float* __restrict__ g0) {
    int m = blockIdx.x * 4 + (threadIdx.x >> 6);
    int lane = threadIdx.x & 63;
    float s = 0.f;
    #pragma unroll
    for (int i = 0; i < 8; ++i) s += GF[m * 512 + lane + i * 64] * zb[lane + i * 64];
    for (int off = 32; off; off >>= 1) s += __shfl_down(s, off);
    if (lane == 0) g0[m] = s;
}

// ---------------- pipelined split-bf16 MFMA NT GEMM, K = 512 ----------------
// Tile 16 rows x 64 cols, 4 waves (wave w -> 16-col tile w). k-chunk 128 (4 chunks),
// register prefetch of next chunk hides L2 latency under 12 MFMAs + 16 ds_reads.
// Two acc chains (hh | hl+lh) for MFMA ILP; summed in epilogue.
// epi: 0 C=acc (+planes if Chi)    1 C=acc+(m==n), planes   2 C=2E-acc, planes
//      5 ADMM: w=v1[n]-(acc+E)-U; U=relu(-w); planes=v1[n]-|w|
//      6 z=acc+E+v1[n]; x'=(1-a)z+a*Xtra; planes            (final z + PGD)
//      7 combo by col-segment: [G | R | W1] -> t-init/planes+U=0 | q0=acc+E[n'] | Xtra=acc
//      8 z=acc+E+v1[n]; emit to Out (bf16/f32 per dtf)
//      9 planes only
#define CH 128
#define LDC 136

__global__ __launch_bounds__(256) void mfma_gemm2(
    const short* __restrict__ Ahi, const short* __restrict__ Alo,
    const short* __restrict__ Bhi, const short* __restrict__ Blo,
    float* __restrict__ C, short* __restrict__ Chi, short* __restrict__ Clo,
    const float* __restrict__ E, const float* __restrict__ v1,
    float* __restrict__ U, float* __restrict__ Xtra,
    const float* __restrict__ dtf, void* __restrict__ Out, int epi)
{
    __shared__ short Ash[2][16 * LDC];
    __shared__ short Bsh[2][64 * LDC];
    const int tid = threadIdx.x;
    const int wv = tid >> 6, ln = tid & 63;
    const int quad = ln >> 4, lr = ln & 15;
    const int m0 = blockIdx.y * 16, n0 = blockIdx.x * 64;

    float4v acc1 = {0.f, 0.f, 0.f, 0.f};
    float4v acc2 = {0.f, 0.f, 0.f, 0.f};

    short8 pa[2], pb[8];
    // prefetch chunk 0
    #pragma unroll
    for (int i = 0; i < 2; ++i) {
        int s = tid + 256 * i; int pl = s >> 8, rem = s & 255, row = rem >> 4, oct = rem & 15;
        const short* P = pl ? Alo : Ahi;
        pa[i] = *(const short8*)(P + (size_t)(m0 + row) * 512 + oct * 8);
    }
    #pragma unroll
    for (int i = 0; i < 8; ++i) {
        int s = tid + 256 * i; int pl = s >> 10, rem = s & 1023, row = rem >> 4, oct = rem & 15;
        const short* P = pl ? Blo : Bhi;
        pb[i] = *(const short8*)(P + (size_t)(n0 + row) * 512 + oct * 8);
    }

    for (int c = 0; c < 4; ++c) {
        if (c) __syncthreads();
        #pragma unroll
        for (int i = 0; i < 2; ++i) {
            int s = tid + 256 * i; int pl = s >> 8, rem = s & 255, row = rem >> 4, oct = rem & 15;
            *(short8*)&Ash[pl][row * LDC + oct * 8] = pa[i];
        }
        #pragma unroll
        for (int i = 0; i < 8; ++i) {
            int s = tid + 256 * i; int pl = s >> 10, rem = s & 1023, row = rem >> 4, oct = rem & 15;
            *(short8*)&Bsh[pl][row * LDC + oct * 8] = pb[i];
        }
        __syncthreads();
        if (c + 1 < 4) {
            int kb = (c + 1) * CH;
            #pragma unroll
            for (int i = 0; i < 2; ++i) {
                int s = tid + 256 * i; int pl = s >> 8, rem = s & 255, row = rem >> 4, oct = rem & 15;
                const short* P = pl ? Alo : Ahi;
                pa[i] = *(const short8*)(P + (size_t)(m0 + row) * 512 + kb + oct * 8);
            }
            #pragma unroll
            for (int i = 0; i < 8; ++i) {
                int s = tid + 256 * i; int pl = s >> 10, rem = s & 1023, row = rem >> 4, oct = rem & 15;
                const short* P = pl ? Blo : Bhi;
                pb[i] = *(const short8*)(P + (size_t)(n0 + row) * 512 + kb + oct * 8);
            }
        }
        #pragma unroll
        for (int ks = 0; ks < 4; ++ks) {
            int ko = (ks * 4 + quad) * 8;
            short8 ah = *(const short8*)&Ash[0][lr * LDC + ko];
            short8 al = *(const short8*)&Ash[1][lr * LDC + ko];
            short8 bh = *(const short8*)&Bsh[0][(wv * 16 + lr) * LDC + ko];
            short8 bl = *(const short8*)&Bsh[1][(wv * 16 + lr) * LDC + ko];
            acc1 = __builtin_amdgcn_mfma_f32_16x16x32_bf16(ah, bh, acc1, 0, 0, 0);
            acc2 = __builtin_amdgcn_mfma_f32_16x16x32_bf16(ah, bl, acc2, 0, 0, 0);
            acc2 = __builtin_amdgcn_mfma_f32_16x16x32_bf16(al, bh, acc2, 0, 0, 0);
        }
    }

    // C/D layout: col = lane&15, row = quad*4 + reg
    #pragma unroll
    for (int r = 0; r < 4; ++r) {
        int m = m0 + quad * 4 + r;
        int n = n0 + wv * 16 + lr;
        float a = acc1[r] + acc2[r];
        if (epi == 7) {
            int seg = n0 >> 9;
            int nl = n - (seg << 9);
            size_t idx = (size_t)m * 512 + nl;
            if (seg == 0) {
                float t0 = fminf(v1[nl], a);
                U[idx] = 0.f;
                split_store(t0, Chi, Clo, idx);
            } else if (seg == 1) {
                C[idx] = a + E[nl];
            } else {
                Xtra[idx] = a;
            }
            continue;
        }
        size_t idx = (size_t)m * 512 + n;
        if (epi == 0) {
            C[idx] = a;
            if (Chi) split_store(a, Chi, Clo, idx);
        } else if (epi == 1) {
            a += (m == n) ? 1.f : 0.f;
            C[idx] = a;
            split_store(a, Chi, Clo, idx);
        } else if (epi == 2) {
            a = 2.f * E[idx] - a;
            C[idx] = a;
            split_store(a, Chi, Clo, idx);
        } else if (epi == 5) {
            float w = v1[n] - (a + E[idx]) - U[idx];
            U[idx] = fmaxf(0.f, -w);
            split_store(v1[n] - fabsf(w), Chi, Clo, idx);
        } else if (epi == 6) {
            float z = a + E[idx] + v1[n];
            float xp = (1.0f - ALPHA) * z + ALPHA * Xtra[idx];
            split_store(xp, Chi, Clo, idx);
        } else if (epi == 8) {
            float z = a + E[idx] + v1[n];
            if (dtf[0] > 0.5f) ((__hip_bfloat16*)Out)[idx] = __float2bfloat16(z);
            else               ((float*)Out)[idx] = z;
        } else {  // 9: planes only
            split_store(a, Chi, Clo, idx);
        }
    }
}

// ---------------- host launcher ----------------

extern "C" void kernel_launch(void* const* d_in, const int* in_sizes, int n_in,
                              void* d_out, int out_size, void* d_ws, size_t ws_size,
                              hipStream_t stream) {
    const void* c_raw = d_in[0];
    const void* G_raw = d_in[1];
    const void* h_raw = d_in[2];
    const void* A_raw = d_in[3];
    const void* b_raw = d_in[4];

    float* w = (float*)d_ws;
    size_t o = 0;
    auto alloc = [&](size_t n) { float* p = w + o; o += (n + 63) & ~(size_t)63; return p; };

    float* cF  = alloc(BB * NN);
    float* GF  = alloc(MI * NN);
    float* AF  = alloc(ME * NN);
    float* hF  = alloc(MI);
    float* bF  = alloc(ME);
    float* Mm  = alloc(NN * NN);
    float* Xf0 = alloc(NN * NN);
    float* Xf1 = alloc(NN * NN);
    float* Rf  = alloc(MI * NN);
    float* Y   = alloc(NN * ME);
    float* T1  = alloc(NN * ME);
    float* Sm  = alloc(ME * ME);
    float* Si  = alloc(ME * ME);
    float* zb  = alloc(NN);
    float* g0  = alloc(MI);
    float* rs  = alloc(NN);
    float* c0s = alloc(16);
    float* dtf = alloc(16);
    float* q0  = alloc(BB * MI);
    float* xW  = alloc(BB * NN);
    float* uB  = alloc(BB * MI);

    short* sbp = (short*)(w + o);
    size_t so = 0;
    auto allocS = [&](size_t n) { short* p = sbp + so; so += (n + 127) & ~(size_t)127; return p; };

    // Bcat = [G(512) ; R(512) ; W1(512)] x 512, contiguous per plane
    short* Bcat_h = allocS(3 * 512 * 512);
    short* Bcat_l = allocS(3 * 512 * 512);
    short* GFh = Bcat_h;             short* GFl = Bcat_l;
    short* Rh  = Bcat_h + 512 * 512; short* Rl  = Bcat_l + 512 * 512;
    short* W1h = Bcat_h + 1024 * 512; short* W1l = Bcat_l + 1024 * 512;

    short* GTh = allocS(NN * MI);  short* GTl = allocS(NN * MI);
    short* Mmh = allocS(NN * NN);  short* Mml = allocS(NN * NN);
    short* X0h = allocS(NN * NN);  short* X0l = allocS(NN * NN);
    short* X1h = allocS(NN * NN);  short* X1l = allocS(NN * NN);
    short* Uh  = allocS(NN * NN);  short* Ul  = allocS(NN * NN);
    short* RTh = allocS(NN * MI);  short* RTl = allocS(NN * MI);
    short* Qh  = allocS(MI * MI);  short* Ql  = allocS(MI * MI);
    short* xh  = allocS(BB * NN);  short* xl  = allocS(BB * NN);
    short* tAh = allocS(BB * MI);  short* tAl = allocS(BB * MI);
    short* tBh = allocS(BB * MI);  short* tBl = allocS(BB * MI);

    dim3 blk(256);
    auto cdiv = [](int a, int b) { return (a + b - 1) / b; };
    dim3 gSq(8, 32);    // 512x512 outputs
    dim3 gBt(8, 64);    // 1024x512 outputs (16-row tiles, 512 blocks = 2/CU)
    dim3 gCombo(24, 64);

    detect_dtype_k<<<1, 256, 0, stream>>>((const unsigned short*)G_raw, dtf);
    ingest_all_k<<<cdiv(BB * NN, 256), blk, 0, stream>>>(
        c_raw, G_raw, h_raw, A_raw, b_raw,
        cF, xh, xl, GF, GFh, GFl, hF, AF, bF, dtf);

    // G^T planes
    transpose_split_k<<<dim3(16, 16), blk, 0, stream>>>(GF, GTh, GTl);

    // M = I + G^T G
    mfma_gemm2<<<gSq, blk, 0, stream>>>(GTh, GTl, GTh, GTl, Mm, Mmh, Mml,
                                        nullptr, nullptr, nullptr, nullptr, nullptr, nullptr, 1);

    // Newton-Schulz inverse
    row_abs_sum_k<<<NN, 64, 0, stream>>>(Mm, rs);
    max_c0_k<<<1, 64, 0, stream>>>(rs, c0s);
    init_X_k<<<cdiv(NN * NN, 256), blk, 0, stream>>>(Xf0, X0h, X0l, c0s);
    float* Xf[2] = {Xf0, Xf1};
    short* Xh[2] = {X0h, X1h};
    short* Xl[2] = {X0l, X1l};
    int cur = 0;
    for (int it = 0; it < NS_ITERS; ++it) {
        int nxt = cur ^ 1;
        // U = X * M (planes only)
        mfma_gemm2<<<gSq, blk, 0, stream>>>(Xh[cur], Xl[cur], Mmh, Mml, nullptr, Uh, Ul,
                                            nullptr, nullptr, nullptr, nullptr, nullptr, nullptr, 9);
        // X' = 2X - U*X
        mfma_gemm2<<<gSq, blk, 0, stream>>>(Uh, Ul, Xh[cur], Xl[cur], Xf[nxt], Xh[nxt], Xl[nxt],
                                            Xf[cur], nullptr, nullptr, nullptr, nullptr, nullptr, 2);
        cur = nxt;
    }
    float* Minv = Xf[cur];

    // Schur pieces
    Y_k<<<NN, blk, 0, stream>>>(Minv, AF, Y);
    Sm_k<<<1, blk, 0, stream>>>(AF, Y, Sm);
    inv16_k<<<1, 64, 0, stream>>>(Sm, Si);
    T1zb_k<<<NN / 16, blk, 0, stream>>>(Y, Si, bF, T1, zb);
    W1_k<<<NN * NN / 256, blk, 0, stream>>>(Minv, T1, Y, W1h, W1l);

    // R = G W1 (f32 + planes into Bcat R slice)
    mfma_gemm2<<<gSq, blk, 0, stream>>>(GFh, GFl, W1h, W1l, Rf, Rh, Rl,
                                        nullptr, nullptr, nullptr, nullptr, nullptr, nullptr, 0);
    transpose_split_k<<<dim3(16, 16), blk, 0, stream>>>(Rf, RTh, RTl);
    // Q = R G^T (planes only)
    mfma_gemm2<<<gSq, blk, 0, stream>>>(Rh, Rl, GFh, GFl, nullptr, Qh, Ql,
                                        nullptr, nullptr, nullptr, nullptr, nullptr, nullptr, 9);
    g0_k<<<NN / 4, blk, 0, stream>>>(GF, zb, g0);

    // 4 projections (x0 = c, planes already in xh/xl from ingest)
    for (int p = 0; p < 4; ++p) {
        // combo: [t0-init | q0 | xW] in one launch, B = [G;R;W1]
        mfma_gemm2<<<gCombo, blk, 0, stream>>>(xh, xl, Bcat_h, Bcat_l, q0, tAh, tAl,
                                               g0, hF, uB, xW, nullptr, nullptr, 7);
        short* th[2] = {tAh, tBh};
        short* tl[2] = {tAl, tBl};
        int tc = 0;
        for (int it = 0; it < ADMM_IT; ++it) {
            int tn = tc ^ 1;
            mfma_gemm2<<<gBt, blk, 0, stream>>>(th[tc], tl[tc], Qh, Ql, nullptr, th[tn], tl[tn],
                                                q0, hF, uB, nullptr, nullptr, nullptr, 5);
            tc = tn;
        }
        // final z (+ PGD split, or emit)
        if (p < 3) {
            mfma_gemm2<<<gBt, blk, 0, stream>>>(th[tc], tl[tc], RTh, RTl, nullptr, xh, xl,
                                                xW, zb, nullptr, cF, nullptr, nullptr, 6);
        } else {
            mfma_gemm2<<<gBt, blk, 0, stream>>>(th[tc], tl[tc], RTh, RTl, nullptr, nullptr, nullptr,
                                                xW, zb, nullptr, nullptr, dtf, d_out, 8);
        }
    }
}